// Round 1
// baseline (2886.768 us; speedup 1.0000x reference)
//
#include <hip/hip_runtime.h>

#define FDIM 128
#define NCLS 16

// ---------------- degree / norm ----------------
__global__ void k_init_deg(float* deg, int n) {
    int i = blockIdx.x * blockDim.x + threadIdx.x;
    if (i < n) deg[i] = 1.0f;  // self-loop contribution
}

__global__ void k_count_deg(const int* __restrict__ dst, float* deg, int e) {
    int i = blockIdx.x * blockDim.x + threadIdx.x;
    if (i < e) atomicAdd(&deg[dst[i]], 1.0f);
}

__global__ void k_finish_dinv(float* deg, int n) {
    int i = blockIdx.x * blockDim.x + threadIdx.x;
    if (i < n) deg[i] = rsqrtf(deg[i]);  // deg >= 1 always (self-loops)
}

// ---------------- GEMM: C[n,128] = A[n,128] @ W[128,128] ----------------
__global__ __launch_bounds__(256) void k_gemm128(const float* __restrict__ A,
                                                 const float* __restrict__ W,
                                                 float* __restrict__ C, int n) {
    __shared__ float ws[128][128];   // 64 KB
    __shared__ float xs[32][128];    // 16 KB
    int t = threadIdx.x;
    const float4* W4 = reinterpret_cast<const float4*>(W);
    float4* ws4 = reinterpret_cast<float4*>(&ws[0][0]);
    for (int i = t; i < 128 * 32; i += 256) ws4[i] = W4[i];

    int row0 = blockIdx.x * 32;
    float4* xs4 = reinterpret_cast<float4*>(&xs[0][0]);
    for (int i = t; i < 32 * 32; i += 256) {
        int r = row0 + (i >> 5);
        xs4[i] = (r < n) ? reinterpret_cast<const float4*>(A)[(size_t)r * 32 + (i & 31)]
                         : make_float4(0.f, 0.f, 0.f, 0.f);
    }
    __syncthreads();

    int tx = t & 31, ty = t >> 5;
    int c0 = tx * 4, r0 = ty * 4;
    float acc[4][4] = {};
    #pragma unroll 4
    for (int k = 0; k < 128; ++k) {
        float4 w4 = *reinterpret_cast<const float4*>(&ws[k][c0]);
        #pragma unroll
        for (int i = 0; i < 4; ++i) {
            float a = xs[r0 + i][k];
            acc[i][0] += a * w4.x;
            acc[i][1] += a * w4.y;
            acc[i][2] += a * w4.z;
            acc[i][3] += a * w4.w;
        }
    }
    #pragma unroll
    for (int i = 0; i < 4; ++i) {
        int r = row0 + r0 + i;
        if (r < n)
            *reinterpret_cast<float4*>(C + (size_t)r * FDIM + c0) =
                make_float4(acc[i][0], acc[i][1], acc[i][2], acc[i][3]);
    }
}

// ---------------- aggregation ----------------
// out[i] = XW[i] * dinv[i]^2   (self-loop term, also initializes out)
__global__ void k_self_loop(const float* __restrict__ XW, const float* __restrict__ dinv,
                            float* __restrict__ out, int n) {
    int idx = blockIdx.x * blockDim.x + threadIdx.x;  // one float4 each
    int total = n * (FDIM / 4);
    if (idx >= total) return;
    int node = idx >> 5;
    float s = dinv[node];
    s = s * s;
    float4 v = reinterpret_cast<const float4*>(XW)[idx];
    reinterpret_cast<float4*>(out)[idx] = make_float4(v.x * s, v.y * s, v.z * s, v.w * s);
}

// one wave (64 lanes) per edge: gather src row, scale, atomic-scatter into dst row
__global__ __launch_bounds__(256) void k_agg_edges(const float* __restrict__ XW,
                                                   const int* __restrict__ src,
                                                   const int* __restrict__ dst,
                                                   const float* __restrict__ dinv,
                                                   float* __restrict__ out, int e) {
    int gid = blockIdx.x * blockDim.x + threadIdx.x;
    int eid = gid >> 6;
    if (eid >= e) return;
    int lane = threadIdx.x & 63;
    int s = src[eid], d = dst[eid];
    float nrm = dinv[s] * dinv[d];
    float2 v = reinterpret_cast<const float2*>(XW + (size_t)s * FDIM)[lane];
    float* drow = out + (size_t)d * FDIM;
    atomicAdd(drow + lane * 2, v.x * nrm);
    atomicAdd(drow + lane * 2 + 1, v.y * nrm);
}

__global__ void k_bias_relu(float* __restrict__ X, const float* __restrict__ b, int n) {
    int idx = blockIdx.x * blockDim.x + threadIdx.x;  // one float4 each
    int total = n * (FDIM / 4);
    if (idx >= total) return;
    int c4 = idx & 31;
    float4 bias = reinterpret_cast<const float4*>(b)[c4];
    float4 v = reinterpret_cast<float4*>(X)[idx];
    v.x = fmaxf(v.x + bias.x, 0.f);
    v.y = fmaxf(v.y + bias.y, 0.f);
    v.z = fmaxf(v.z + bias.z, 0.f);
    v.w = fmaxf(v.w + bias.w, 0.f);
    reinterpret_cast<float4*>(X)[idx] = v;
}

// ---------------- classifier + softmax ----------------
// 16 nodes/block; 16 threads per node (one per class); softmax via shfl within 16-lane group
__global__ __launch_bounds__(256) void k_classifier(const float* __restrict__ H,
                                                    const float* __restrict__ Wl,
                                                    const float* __restrict__ bl,
                                                    float* __restrict__ out, int n) {
    __shared__ float wl[FDIM * NCLS];  // 8 KB
    int t = threadIdx.x;
    for (int i = t; i < FDIM * NCLS / 4; i += 256)
        reinterpret_cast<float4*>(wl)[i] = reinterpret_cast<const float4*>(Wl)[i];
    __syncthreads();

    int node = blockIdx.x * 16 + (t >> 4);
    int c = t & 15;
    if (node >= n) return;
    const float* h = H + (size_t)node * FDIM;
    float acc = bl[c];
    #pragma unroll 8
    for (int k = 0; k < FDIM; ++k) acc += h[k] * wl[k * NCLS + c];

    float m = acc;
    #pragma unroll
    for (int off = 8; off >= 1; off >>= 1) m = fmaxf(m, __shfl_xor(m, off, 16));
    float ev = __expf(acc - m);
    float sum = ev;
    #pragma unroll
    for (int off = 8; off >= 1; off >>= 1) sum += __shfl_xor(sum, off, 16);
    out[(size_t)node * NCLS + c] = ev / sum;
}

extern "C" void kernel_launch(void* const* d_in, const int* in_sizes, int n_in,
                              void* d_out, int out_size, void* d_ws, size_t ws_size,
                              hipStream_t stream) {
    const float* x  = (const float*)d_in[0];
    const int*   ei = (const int*)d_in[1];
    const float* W1 = (const float*)d_in[2];
    const float* b1 = (const float*)d_in[3];
    const float* W2 = (const float*)d_in[4];
    const float* b2 = (const float*)d_in[5];
    const float* Wl = (const float*)d_in[6];
    const float* bl = (const float*)d_in[7];
    float* out = (float*)d_out;

    int n = in_sizes[0] / FDIM;
    int e = in_sizes[1] / 2;
    const int* src = ei;
    const int* dst = ei + e;

    float* dinv = (float*)d_ws;                    // n floats
    float* bufA = dinv + n;                        // n*128 floats
    float* bufB = bufA + (size_t)n * FDIM;         // n*128 floats

    int bn = (n + 255) / 256;
    int be = (e + 255) / 256;
    int bvec = (n * (FDIM / 4) + 255) / 256;
    int bedge = (int)(((size_t)e * 64 + 255) / 256);

    // degrees -> dinv
    k_init_deg<<<bn, 256, 0, stream>>>(dinv, n);
    k_count_deg<<<be, 256, 0, stream>>>(dst, dinv, e);
    k_finish_dinv<<<bn, 256, 0, stream>>>(dinv, n);

    // layer 1
    k_gemm128<<<(n + 31) / 32, 256, 0, stream>>>(x, W1, bufA, n);
    k_self_loop<<<bvec, 256, 0, stream>>>(bufA, dinv, bufB, n);
    k_agg_edges<<<bedge, 256, 0, stream>>>(bufA, src, dst, dinv, bufB, e);
    k_bias_relu<<<bvec, 256, 0, stream>>>(bufB, b1, n);

    // layer 2
    k_gemm128<<<(n + 31) / 32, 256, 0, stream>>>(bufB, W2, bufA, n);
    k_self_loop<<<bvec, 256, 0, stream>>>(bufA, dinv, bufB, n);
    k_agg_edges<<<bedge, 256, 0, stream>>>(bufA, src, dst, dinv, bufB, e);
    k_bias_relu<<<bvec, 256, 0, stream>>>(bufB, b2, n);

    // classifier + softmax
    k_classifier<<<(n + 15) / 16, 256, 0, stream>>>(bufB, Wl, bl, out, n);
}

// Round 2
// 881.519 us; speedup vs baseline: 3.2748x; 3.2748x over previous
//
#include <hip/hip_runtime.h>

#define FDIM 128
#define NCLS 16

// ---------------- CSR build ----------------
__global__ void k_zero_cnt(int* cnt, int n) {
    int i = blockIdx.x * blockDim.x + threadIdx.x;
    if (i < n) cnt[i] = 0;
}

__global__ void k_count(const int* __restrict__ dst, int* cnt, int e) {
    int i = blockIdx.x * blockDim.x + threadIdx.x;
    if (i < e) atomicAdd(&cnt[dst[i]], 1);
}

__global__ void k_dinv(const int* __restrict__ cnt, float* __restrict__ dinv, int n) {
    int i = blockIdx.x * blockDim.x + threadIdx.x;
    if (i < n) dinv[i] = rsqrtf((float)(cnt[i] + 1));  // +1 self-loop
}

// single-block exclusive scan of cnt[0..n) -> row_ptr[0..n], copy to cursor
__global__ __launch_bounds__(1024) void k_scan(const int* __restrict__ cnt,
                                               int* __restrict__ row_ptr,
                                               int* __restrict__ cursor, int n) {
    __shared__ int sums[1024];
    int t = threadIdx.x;
    int chunk = (n + 1023) >> 10;
    int lo = t * chunk, hi = min(lo + chunk, n);
    int s = 0;
    for (int i = lo; i < hi; ++i) s += cnt[i];
    sums[t] = s;
    __syncthreads();
    for (int off = 1; off < 1024; off <<= 1) {
        int v = (t >= off) ? sums[t - off] : 0;
        __syncthreads();
        sums[t] += v;
        __syncthreads();
    }
    int excl = (t == 0) ? 0 : sums[t - 1];
    for (int i = lo; i < hi; ++i) {
        int c = cnt[i];
        row_ptr[i] = excl;
        cursor[i]  = excl;
        excl += c;
    }
    if (t == 1023) row_ptr[n] = sums[1023];
}

__global__ void k_scatter(const int* __restrict__ src, const int* __restrict__ dst,
                          int* cursor, int* __restrict__ csr_src, int e) {
    int i = blockIdx.x * blockDim.x + threadIdx.x;
    if (i >= e) return;
    int pos = atomicAdd(&cursor[dst[i]], 1);
    csr_src[pos] = src[i];
}

// ---------------- GEMM: Y[n,128] = (A[n,128] @ W[128,128]) * dinv[row] ----------------
__global__ __launch_bounds__(256) void k_gemm128(const float* __restrict__ A,
                                                 const float* __restrict__ W,
                                                 const float* __restrict__ dinv,
                                                 float* __restrict__ C, int n) {
    __shared__ float ws[128][128];   // 64 KB
    __shared__ float xs[32][128];    // 16 KB
    int t = threadIdx.x;
    const float4* W4 = reinterpret_cast<const float4*>(W);
    float4* ws4 = reinterpret_cast<float4*>(&ws[0][0]);
    for (int i = t; i < 128 * 32; i += 256) ws4[i] = W4[i];

    int row0 = blockIdx.x * 32;
    float4* xs4 = reinterpret_cast<float4*>(&xs[0][0]);
    for (int i = t; i < 32 * 32; i += 256) {
        int r = row0 + (i >> 5);
        xs4[i] = (r < n) ? reinterpret_cast<const float4*>(A)[(size_t)r * 32 + (i & 31)]
                         : make_float4(0.f, 0.f, 0.f, 0.f);
    }
    __syncthreads();

    int tx = t & 31, ty = t >> 5;
    int c0 = tx * 4, r0 = ty * 4;
    float acc[4][4] = {};
    #pragma unroll 4
    for (int k = 0; k < 128; ++k) {
        float4 w4 = *reinterpret_cast<const float4*>(&ws[k][c0]);
        #pragma unroll
        for (int i = 0; i < 4; ++i) {
            float a = xs[r0 + i][k];
            acc[i][0] += a * w4.x;
            acc[i][1] += a * w4.y;
            acc[i][2] += a * w4.z;
            acc[i][3] += a * w4.w;
        }
    }
    #pragma unroll
    for (int i = 0; i < 4; ++i) {
        int r = row0 + r0 + i;
        if (r < n) {
            float s = dinv[r];
            *reinterpret_cast<float4*>(C + (size_t)r * FDIM + c0) =
                make_float4(acc[i][0] * s, acc[i][1] * s, acc[i][2] * s, acc[i][3] * s);
        }
    }
}

// ---------------- aggregation: out[d] = relu(dinv[d]*(Y[d] + sum Y[src]) + b) ----------------
// one wave per node; lane covers float2 of the 128-dim row
__global__ __launch_bounds__(256) void k_agg_csr(const float* __restrict__ Y,
                                                 const int* __restrict__ csr_src,
                                                 const int* __restrict__ row_ptr,
                                                 const float* __restrict__ dinv,
                                                 const float* __restrict__ bias,
                                                 float* __restrict__ out, int n) {
    int node = blockIdx.x * 4 + (threadIdx.x >> 6);
    if (node >= n) return;
    int lane = threadIdx.x & 63;

    float2 acc = reinterpret_cast<const float2*>(Y + (size_t)node * FDIM)[lane];  // self term
    int beg = row_ptr[node], end = row_ptr[node + 1];

    for (int j0 = beg; j0 < end; j0 += 64) {
        int cnt = min(64, end - j0);
        int myidx = (j0 + lane < end) ? csr_src[j0 + lane] : 0;
        int k = 0;
        for (; k + 4 <= cnt; k += 4) {
            int s0 = __shfl(myidx, k, 64);
            int s1 = __shfl(myidx, k + 1, 64);
            int s2 = __shfl(myidx, k + 2, 64);
            int s3 = __shfl(myidx, k + 3, 64);
            float2 v0 = reinterpret_cast<const float2*>(Y + (size_t)s0 * FDIM)[lane];
            float2 v1 = reinterpret_cast<const float2*>(Y + (size_t)s1 * FDIM)[lane];
            float2 v2 = reinterpret_cast<const float2*>(Y + (size_t)s2 * FDIM)[lane];
            float2 v3 = reinterpret_cast<const float2*>(Y + (size_t)s3 * FDIM)[lane];
            acc.x += (v0.x + v1.x) + (v2.x + v3.x);
            acc.y += (v0.y + v1.y) + (v2.y + v3.y);
        }
        for (; k < cnt; ++k) {
            int s = __shfl(myidx, k, 64);
            float2 v = reinterpret_cast<const float2*>(Y + (size_t)s * FDIM)[lane];
            acc.x += v.x;
            acc.y += v.y;
        }
    }

    float di = dinv[node];
    float2 b = reinterpret_cast<const float2*>(bias)[lane];
    float2 r;
    r.x = fmaxf(acc.x * di + b.x, 0.f);
    r.y = fmaxf(acc.y * di + b.y, 0.f);
    reinterpret_cast<float2*>(out + (size_t)node * FDIM)[lane] = r;
}

// ---------------- classifier + softmax ----------------
__global__ __launch_bounds__(256) void k_classifier(const float* __restrict__ H,
                                                    const float* __restrict__ Wl,
                                                    const float* __restrict__ bl,
                                                    float* __restrict__ out, int n) {
    __shared__ float wl[FDIM * NCLS];  // 8 KB
    int t = threadIdx.x;
    for (int i = t; i < FDIM * NCLS / 4; i += 256)
        reinterpret_cast<float4*>(wl)[i] = reinterpret_cast<const float4*>(Wl)[i];
    __syncthreads();

    int node = blockIdx.x * 16 + (t >> 4);
    int c = t & 15;
    if (node >= n) return;
    const float* h = H + (size_t)node * FDIM;
    float acc = bl[c];
    #pragma unroll 8
    for (int k = 0; k < FDIM; ++k) acc += h[k] * wl[k * NCLS + c];

    float m = acc;
    #pragma unroll
    for (int off = 8; off >= 1; off >>= 1) m = fmaxf(m, __shfl_xor(m, off, 16));
    float ev = __expf(acc - m);
    float sum = ev;
    #pragma unroll
    for (int off = 8; off >= 1; off >>= 1) sum += __shfl_xor(sum, off, 16);
    out[(size_t)node * NCLS + c] = ev / sum;
}

extern "C" void kernel_launch(void* const* d_in, const int* in_sizes, int n_in,
                              void* d_out, int out_size, void* d_ws, size_t ws_size,
                              hipStream_t stream) {
    const float* x  = (const float*)d_in[0];
    const int*   ei = (const int*)d_in[1];
    const float* W1 = (const float*)d_in[2];
    const float* b1 = (const float*)d_in[3];
    const float* W2 = (const float*)d_in[4];
    const float* b2 = (const float*)d_in[5];
    const float* Wl = (const float*)d_in[6];
    const float* bl = (const float*)d_in[7];
    float* out = (float*)d_out;

    int n = in_sizes[0] / FDIM;
    int e = in_sizes[1] / 2;
    const int* src = ei;
    const int* dst = ei + e;

    // workspace layout
    float* dinv   = (float*)d_ws;                      // n
    int*   cnt    = (int*)(dinv + n);                  // n
    int*   row_ptr= cnt + n;                           // n+1
    int*   cursor = row_ptr + n + 1;                   // n
    int*   csr_src= cursor + n;                        // e
    float* bufA   = (float*)(csr_src + e);             // n*128
    float* bufB   = bufA + (size_t)n * FDIM;           // n*128

    int bn = (n + 255) / 256;
    int be = (e + 255) / 256;

    // CSR + norms
    k_zero_cnt<<<bn, 256, 0, stream>>>(cnt, n);
    k_count<<<be, 256, 0, stream>>>(dst, cnt, e);
    k_dinv<<<bn, 256, 0, stream>>>(cnt, dinv, n);
    k_scan<<<1, 1024, 0, stream>>>(cnt, row_ptr, cursor, n);
    k_scatter<<<be, 256, 0, stream>>>(src, dst, cursor, csr_src, e);

    int bg = (n + 31) / 32;
    int ba = (n + 3) / 4;

    // layer 1
    k_gemm128<<<bg, 256, 0, stream>>>(x, W1, dinv, bufA, n);
    k_agg_csr<<<ba, 256, 0, stream>>>(bufA, csr_src, row_ptr, dinv, b1, bufB, n);

    // layer 2
    k_gemm128<<<bg, 256, 0, stream>>>(bufB, W2, dinv, bufA, n);
    k_agg_csr<<<ba, 256, 0, stream>>>(bufA, csr_src, row_ptr, dinv, b2, bufB, n);

    // classifier + softmax
    k_classifier<<<(n + 15) / 16, 256, 0, stream>>>(bufB, Wl, bl, out, n);
}

// Round 3
// 671.895 us; speedup vs baseline: 4.2965x; 1.3120x over previous
//
#include <hip/hip_runtime.h>

#define FDIM 128
#define NCLS 16

#define SCAN_T 256
#define SCAN_I 8
#define SCAN_CHUNK (SCAN_T * SCAN_I)  // 2048 elements per block

// ---------------- CSR build ----------------
__global__ void k_zero_cnt(int* cnt, int n) {
    int i = blockIdx.x * blockDim.x + threadIdx.x;
    if (i < n) cnt[i] = 0;
}

__global__ void k_count(const int* __restrict__ dst, int* cnt, int e) {
    int i = blockIdx.x * blockDim.x + threadIdx.x;
    if (i < e) atomicAdd(&cnt[dst[i]], 1);
}

__global__ void k_dinv(const int* __restrict__ cnt, float* __restrict__ dinv, int n) {
    int i = blockIdx.x * blockDim.x + threadIdx.x;
    if (i < n) dinv[i] = rsqrtf((float)(cnt[i] + 1));  // +1 self-loop
}

// ---- 3-phase device-wide exclusive scan of cnt -> row_ptr/cursor ----
// phase 1: block-local exclusive scan, per-block total
__global__ __launch_bounds__(SCAN_T) void k_scan1(const int* __restrict__ cnt,
                                                  int* __restrict__ excl,
                                                  int* __restrict__ blockSum, int n) {
    __shared__ int ts[SCAN_T];
    int b = blockIdx.x, t = threadIdx.x;
    int base = b * SCAN_CHUNK + t * SCAN_I;
    int v[SCAN_I];
    int s = 0;
    #pragma unroll
    for (int i = 0; i < SCAN_I; ++i) {
        int idx = base + i;
        v[i] = (idx < n) ? cnt[idx] : 0;
        s += v[i];
    }
    ts[t] = s;
    __syncthreads();
    for (int off = 1; off < SCAN_T; off <<= 1) {
        int x = (t >= off) ? ts[t - off] : 0;
        __syncthreads();
        ts[t] += x;
        __syncthreads();
    }
    int ex = (t == 0) ? 0 : ts[t - 1];
    #pragma unroll
    for (int i = 0; i < SCAN_I; ++i) {
        int idx = base + i;
        if (idx < n) excl[idx] = ex;
        ex += v[i];
    }
    if (t == SCAN_T - 1) blockSum[b] = ts[SCAN_T - 1];
}

// phase 2: single block exclusive-scans the block totals (nb <= 1024)
__global__ __launch_bounds__(1024) void k_scan2(int* blockSum, int* total, int nb) {
    __shared__ int ts[1024];
    int t = threadIdx.x;
    int v = (t < nb) ? blockSum[t] : 0;
    ts[t] = v;
    __syncthreads();
    for (int off = 1; off < 1024; off <<= 1) {
        int x = (t >= off) ? ts[t - off] : 0;
        __syncthreads();
        ts[t] += x;
        __syncthreads();
    }
    if (t < nb) blockSum[t] = (t == 0) ? 0 : ts[t - 1];
    if (t == 1023) *total = ts[1023];
}

// phase 3: add block offsets, copy to cursor, write row_ptr[n]
__global__ void k_scan3(int* __restrict__ row_ptr, int* __restrict__ cursor,
                        const int* __restrict__ blockSum, const int* __restrict__ total,
                        int n) {
    int i = blockIdx.x * blockDim.x + threadIdx.x;
    if (i < n) {
        int v = row_ptr[i] + blockSum[i / SCAN_CHUNK];
        row_ptr[i] = v;
        cursor[i] = v;
    }
    if (i == 0) row_ptr[n] = *total;
}

__global__ void k_scatter(const int* __restrict__ src, const int* __restrict__ dst,
                          int* cursor, int* __restrict__ csr_src, int e) {
    int i = blockIdx.x * blockDim.x + threadIdx.x;
    if (i >= e) return;
    int pos = atomicAdd(&cursor[dst[i]], 1);
    csr_src[pos] = src[i];
}

// ---------------- GEMM: Y[n,128] = (A[n,128] @ W[128,128]) * dinv[row] ----------------
__global__ __launch_bounds__(256) void k_gemm128(const float* __restrict__ A,
                                                 const float* __restrict__ W,
                                                 const float* __restrict__ dinv,
                                                 float* __restrict__ C, int n) {
    __shared__ float ws[128][128];   // 64 KB
    __shared__ float xs[32][128];    // 16 KB
    int t = threadIdx.x;
    const float4* W4 = reinterpret_cast<const float4*>(W);
    float4* ws4 = reinterpret_cast<float4*>(&ws[0][0]);
    for (int i = t; i < 128 * 32; i += 256) ws4[i] = W4[i];

    int row0 = blockIdx.x * 32;
    float4* xs4 = reinterpret_cast<float4*>(&xs[0][0]);
    for (int i = t; i < 32 * 32; i += 256) {
        int r = row0 + (i >> 5);
        xs4[i] = (r < n) ? reinterpret_cast<const float4*>(A)[(size_t)r * 32 + (i & 31)]
                         : make_float4(0.f, 0.f, 0.f, 0.f);
    }
    __syncthreads();

    int tx = t & 31, ty = t >> 5;
    int c0 = tx * 4, r0 = ty * 4;
    float acc[4][4] = {};
    #pragma unroll 4
    for (int k = 0; k < 128; ++k) {
        float4 w4 = *reinterpret_cast<const float4*>(&ws[k][c0]);
        #pragma unroll
        for (int i = 0; i < 4; ++i) {
            float a = xs[r0 + i][k];
            acc[i][0] += a * w4.x;
            acc[i][1] += a * w4.y;
            acc[i][2] += a * w4.z;
            acc[i][3] += a * w4.w;
        }
    }
    #pragma unroll
    for (int i = 0; i < 4; ++i) {
        int r = row0 + r0 + i;
        if (r < n) {
            float s = dinv[r];
            *reinterpret_cast<float4*>(C + (size_t)r * FDIM + c0) =
                make_float4(acc[i][0] * s, acc[i][1] * s, acc[i][2] * s, acc[i][3] * s);
        }
    }
}

// ---------------- aggregation: out[d] = relu(dinv[d]*(Y[d] + sum Y[src]) + b) ----------------
__global__ __launch_bounds__(256) void k_agg_csr(const float* __restrict__ Y,
                                                 const int* __restrict__ csr_src,
                                                 const int* __restrict__ row_ptr,
                                                 const float* __restrict__ dinv,
                                                 const float* __restrict__ bias,
                                                 float* __restrict__ out, int n) {
    int node = blockIdx.x * 4 + (threadIdx.x >> 6);
    if (node >= n) return;
    int lane = threadIdx.x & 63;

    float2 acc = reinterpret_cast<const float2*>(Y + (size_t)node * FDIM)[lane];  // self term
    int beg = row_ptr[node], end = row_ptr[node + 1];

    for (int j0 = beg; j0 < end; j0 += 64) {
        int cnt = min(64, end - j0);
        int myidx = (j0 + lane < end) ? csr_src[j0 + lane] : 0;
        int k = 0;
        for (; k + 4 <= cnt; k += 4) {
            int s0 = __shfl(myidx, k, 64);
            int s1 = __shfl(myidx, k + 1, 64);
            int s2 = __shfl(myidx, k + 2, 64);
            int s3 = __shfl(myidx, k + 3, 64);
            float2 v0 = reinterpret_cast<const float2*>(Y + (size_t)s0 * FDIM)[lane];
            float2 v1 = reinterpret_cast<const float2*>(Y + (size_t)s1 * FDIM)[lane];
            float2 v2 = reinterpret_cast<const float2*>(Y + (size_t)s2 * FDIM)[lane];
            float2 v3 = reinterpret_cast<const float2*>(Y + (size_t)s3 * FDIM)[lane];
            acc.x += (v0.x + v1.x) + (v2.x + v3.x);
            acc.y += (v0.y + v1.y) + (v2.y + v3.y);
        }
        for (; k < cnt; ++k) {
            int s = __shfl(myidx, k, 64);
            float2 v = reinterpret_cast<const float2*>(Y + (size_t)s * FDIM)[lane];
            acc.x += v.x;
            acc.y += v.y;
        }
    }

    float di = dinv[node];
    float2 b = reinterpret_cast<const float2*>(bias)[lane];
    float2 r;
    r.x = fmaxf(acc.x * di + b.x, 0.f);
    r.y = fmaxf(acc.y * di + b.y, 0.f);
    reinterpret_cast<float2*>(out + (size_t)node * FDIM)[lane] = r;
}

// ---------------- classifier + softmax ----------------
__global__ __launch_bounds__(256) void k_classifier(const float* __restrict__ H,
                                                    const float* __restrict__ Wl,
                                                    const float* __restrict__ bl,
                                                    float* __restrict__ out, int n) {
    __shared__ float wl[FDIM * NCLS];  // 8 KB
    int t = threadIdx.x;
    for (int i = t; i < FDIM * NCLS / 4; i += 256)
        reinterpret_cast<float4*>(wl)[i] = reinterpret_cast<const float4*>(Wl)[i];
    __syncthreads();

    int node = blockIdx.x * 16 + (t >> 4);
    int c = t & 15;
    if (node >= n) return;
    const float* h = H + (size_t)node * FDIM;
    float acc = bl[c];
    #pragma unroll 8
    for (int k = 0; k < FDIM; ++k) acc += h[k] * wl[k * NCLS + c];

    float m = acc;
    #pragma unroll
    for (int off = 8; off >= 1; off >>= 1) m = fmaxf(m, __shfl_xor(m, off, 16));
    float ev = __expf(acc - m);
    float sum = ev;
    #pragma unroll
    for (int off = 8; off >= 1; off >>= 1) sum += __shfl_xor(sum, off, 16);
    out[(size_t)node * NCLS + c] = ev / sum;
}

extern "C" void kernel_launch(void* const* d_in, const int* in_sizes, int n_in,
                              void* d_out, int out_size, void* d_ws, size_t ws_size,
                              hipStream_t stream) {
    const float* x  = (const float*)d_in[0];
    const int*   ei = (const int*)d_in[1];
    const float* W1 = (const float*)d_in[2];
    const float* b1 = (const float*)d_in[3];
    const float* W2 = (const float*)d_in[4];
    const float* b2 = (const float*)d_in[5];
    const float* Wl = (const float*)d_in[6];
    const float* bl = (const float*)d_in[7];
    float* out = (float*)d_out;

    int n = in_sizes[0] / FDIM;
    int e = in_sizes[1] / 2;
    const int* src = ei;
    const int* dst = ei + e;

    int nb = (n + SCAN_CHUNK - 1) / SCAN_CHUNK;  // scan phase-1 blocks (<=1024)

    // workspace layout
    float* dinv    = (float*)d_ws;                     // n
    int*   cnt     = (int*)(dinv + n);                 // n
    int*   row_ptr = cnt + n;                          // n+1
    int*   cursor  = row_ptr + n + 1;                  // n
    int*   blockSum= cursor + n;                       // nb (<=1024)
    int*   total   = blockSum + 1024;                  // 1
    int*   csr_src = total + 1;                        // e
    float* bufA    = (float*)(csr_src + e);            // n*128
    float* bufB    = bufA + (size_t)n * FDIM;          // n*128

    int bn = (n + 255) / 256;
    int be = (e + 255) / 256;

    // CSR + norms
    k_zero_cnt<<<bn, 256, 0, stream>>>(cnt, n);
    k_count<<<be, 256, 0, stream>>>(dst, cnt, e);
    k_dinv<<<bn, 256, 0, stream>>>(cnt, dinv, n);
    k_scan1<<<nb, SCAN_T, 0, stream>>>(cnt, row_ptr, blockSum, n);
    k_scan2<<<1, 1024, 0, stream>>>(blockSum, total, nb);
    k_scan3<<<bn, 256, 0, stream>>>(row_ptr, cursor, blockSum, total, n);
    k_scatter<<<be, 256, 0, stream>>>(src, dst, cursor, csr_src, e);

    int bg = (n + 31) / 32;
    int ba = (n + 3) / 4;

    // layer 1
    k_gemm128<<<bg, 256, 0, stream>>>(x, W1, dinv, bufA, n);
    k_agg_csr<<<ba, 256, 0, stream>>>(bufA, csr_src, row_ptr, dinv, b1, bufB, n);

    // layer 2
    k_gemm128<<<bg, 256, 0, stream>>>(bufB, W2, dinv, bufA, n);
    k_agg_csr<<<ba, 256, 0, stream>>>(bufA, csr_src, row_ptr, dinv, b2, bufB, n);

    // classifier + softmax
    k_classifier<<<(n + 15) / 16, 256, 0, stream>>>(bufB, Wl, bl, out, n);
}

// Round 4
// 660.103 us; speedup vs baseline: 4.3732x; 1.0179x over previous
//
#include <hip/hip_runtime.h>

#define FDIM 128
#define NCLS 16

#define SCAN_T 256
#define SCAN_I 8
#define SCAN_CHUNK (SCAN_T * SCAN_I)  // 2048 elements per block

// ---------------- CSR build ----------------
__global__ void k_zero_cnt(int* cnt, int n) {
    int i = blockIdx.x * blockDim.x + threadIdx.x;
    if (i < n) cnt[i] = 0;
}

__global__ void k_count(const int* __restrict__ dst, int* cnt, int e) {
    int i = blockIdx.x * blockDim.x + threadIdx.x;
    if (i < e) atomicAdd(&cnt[dst[i]], 1);
}

// phase 1: block-local exclusive scan, per-block total; also computes dinv
__global__ __launch_bounds__(SCAN_T) void k_scan1(const int* __restrict__ cnt,
                                                  int* __restrict__ excl,
                                                  int* __restrict__ blockSum,
                                                  float* __restrict__ dinv, int n) {
    __shared__ int ts[SCAN_T];
    int b = blockIdx.x, t = threadIdx.x;
    int base = b * SCAN_CHUNK + t * SCAN_I;
    int v[SCAN_I];
    int s = 0;
    #pragma unroll
    for (int i = 0; i < SCAN_I; ++i) {
        int idx = base + i;
        v[i] = (idx < n) ? cnt[idx] : 0;
        if (idx < n) dinv[idx] = rsqrtf((float)(v[i] + 1));  // +1 self-loop
        s += v[i];
    }
    ts[t] = s;
    __syncthreads();
    for (int off = 1; off < SCAN_T; off <<= 1) {
        int x = (t >= off) ? ts[t - off] : 0;
        __syncthreads();
        ts[t] += x;
        __syncthreads();
    }
    int ex = (t == 0) ? 0 : ts[t - 1];
    #pragma unroll
    for (int i = 0; i < SCAN_I; ++i) {
        int idx = base + i;
        if (idx < n) excl[idx] = ex;
        ex += v[i];
    }
    if (t == SCAN_T - 1) blockSum[b] = ts[SCAN_T - 1];
}

// phase 2: single block exclusive-scans the block totals (nb <= 1024)
__global__ __launch_bounds__(1024) void k_scan2(int* blockSum, int* total, int nb) {
    __shared__ int ts[1024];
    int t = threadIdx.x;
    int v = (t < nb) ? blockSum[t] : 0;
    ts[t] = v;
    __syncthreads();
    for (int off = 1; off < 1024; off <<= 1) {
        int x = (t >= off) ? ts[t - off] : 0;
        __syncthreads();
        ts[t] += x;
        __syncthreads();
    }
    if (t < nb) blockSum[t] = (t == 0) ? 0 : ts[t - 1];
    if (t == 1023) *total = ts[1023];
}

// phase 3: add block offsets, copy to cursor, write row_ptr[n]
__global__ void k_scan3(int* __restrict__ row_ptr, int* __restrict__ cursor,
                        const int* __restrict__ blockSum, const int* __restrict__ total,
                        int n) {
    int i = blockIdx.x * blockDim.x + threadIdx.x;
    if (i < n) {
        int v = row_ptr[i] + blockSum[i / SCAN_CHUNK];
        row_ptr[i] = v;
        cursor[i] = v;
    }
    if (i == 0) row_ptr[n] = *total;
}

__global__ void k_scatter(const int* __restrict__ src, const int* __restrict__ dst,
                          int* cursor, int* __restrict__ csr_src, int e) {
    int i = blockIdx.x * blockDim.x + threadIdx.x;
    if (i >= e) return;
    int pos = atomicAdd(&cursor[dst[i]], 1);
    csr_src[pos] = src[i];
}

// ---------------- GEMM: Y[n,128] = (A[n,128] @ W[128,128]) * dinv[row] ----------------
// 512 threads, 128x128 tile, 8 rows x 4 cols per thread
#define GT 512
#define GR 128
__global__ __launch_bounds__(GT) void k_gemm128(const float* __restrict__ A,
                                                const float* __restrict__ W,
                                                const float* __restrict__ dinv,
                                                float* __restrict__ C, int n) {
    __shared__ float ws[128 * 128];   // [k][c], 64 KB
    __shared__ float xs[GR * 132];    // [r][k] padded to 132, 67.6 KB
    int t = threadIdx.x;
    const float4* W4 = reinterpret_cast<const float4*>(W);
    #pragma unroll
    for (int i = t; i < 128 * 32; i += GT)
        reinterpret_cast<float4*>(ws)[i] = W4[i];

    int row0 = blockIdx.x * GR;
    for (int i = t; i < GR * 32; i += GT) {
        int r = i >> 5, k4 = i & 31;
        float4 v = (row0 + r < n)
                       ? reinterpret_cast<const float4*>(A)[(size_t)(row0 + r) * 32 + k4]
                       : make_float4(0.f, 0.f, 0.f, 0.f);
        *reinterpret_cast<float4*>(&xs[r * 132 + k4 * 4]) = v;
    }
    __syncthreads();

    int tc = t & 31, tr = t >> 5;   // tr 0..15
    int c0 = tc * 4, r0 = tr * 8;
    float4 acc[8] = {};
    for (int k = 0; k < 128; k += 4) {
        float4 a[8];
        #pragma unroll
        for (int i = 0; i < 8; ++i)
            a[i] = *reinterpret_cast<const float4*>(&xs[(r0 + i) * 132 + k]);
        #pragma unroll
        for (int kk = 0; kk < 4; ++kk) {
            float4 w4 = *reinterpret_cast<const float4*>(&ws[(k + kk) * 128 + c0]);
            #pragma unroll
            for (int i = 0; i < 8; ++i) {
                float av = (kk == 0) ? a[i].x : (kk == 1) ? a[i].y : (kk == 2) ? a[i].z : a[i].w;
                acc[i].x += av * w4.x;
                acc[i].y += av * w4.y;
                acc[i].z += av * w4.z;
                acc[i].w += av * w4.w;
            }
        }
    }
    #pragma unroll
    for (int i = 0; i < 8; ++i) {
        int r = row0 + r0 + i;
        if (r < n) {
            float s = dinv[r];
            reinterpret_cast<float4*>(C)[(size_t)r * 32 + tc] =
                make_float4(acc[i].x * s, acc[i].y * s, acc[i].z * s, acc[i].w * s);
        }
    }
}

// ---------------- aggregation (+ optional fused classifier/softmax) ----------------
// one wave per node; 32 lanes x float4 cover the row; the two wave-halves
// process interleaved edges concurrently (8 gathers in flight per wave)
template <bool FUSE>
__global__ __launch_bounds__(256) void k_agg(const float* __restrict__ Y,
                                             const int* __restrict__ csr_src,
                                             const int* __restrict__ row_ptr,
                                             const float* __restrict__ dinv,
                                             const float* __restrict__ bias,
                                             const float* __restrict__ Wl,
                                             const float* __restrict__ bl,
                                             float* __restrict__ out, int n) {
    __shared__ float s_wl[NCLS * FDIM];  // transposed: [c][k], 8 KB
    __shared__ float s_bl[NCLS];
    if (FUSE) {
        // stage Wl transposed
        for (int i = threadIdx.x; i < FDIM * NCLS / 4; i += 256) {
            int k = i >> 2, c4 = (i & 3) * 4;
            float4 v = reinterpret_cast<const float4*>(Wl)[i];
            s_wl[(c4 + 0) * FDIM + k] = v.x;
            s_wl[(c4 + 1) * FDIM + k] = v.y;
            s_wl[(c4 + 2) * FDIM + k] = v.z;
            s_wl[(c4 + 3) * FDIM + k] = v.w;
        }
        if (threadIdx.x < NCLS) s_bl[threadIdx.x] = bl[threadIdx.x];
        __syncthreads();
    }

    int node = blockIdx.x * 4 + (threadIdx.x >> 6);
    if (node >= n) return;
    int lane = threadIdx.x & 63;
    int half = lane >> 5, l32 = lane & 31;

    const float4* Y4 = reinterpret_cast<const float4*>(Y);
    float4 acc = make_float4(0.f, 0.f, 0.f, 0.f);
    if (half == 0) acc = Y4[(size_t)node * 32 + l32];  // self term once

    int beg = row_ptr[node], end = row_ptr[node + 1];
    int j = beg + half;  // this half: beg+half, +2, +4, ...
    for (; j + 6 < end; j += 8) {
        int s0 = csr_src[j];
        int s1 = csr_src[j + 2];
        int s2 = csr_src[j + 4];
        int s3 = csr_src[j + 6];
        float4 v0 = Y4[(size_t)s0 * 32 + l32];
        float4 v1 = Y4[(size_t)s1 * 32 + l32];
        float4 v2 = Y4[(size_t)s2 * 32 + l32];
        float4 v3 = Y4[(size_t)s3 * 32 + l32];
        acc.x += (v0.x + v1.x) + (v2.x + v3.x);
        acc.y += (v0.y + v1.y) + (v2.y + v3.y);
        acc.z += (v0.z + v1.z) + (v2.z + v3.z);
        acc.w += (v0.w + v1.w) + (v2.w + v3.w);
    }
    for (; j < end; j += 2) {
        int s = csr_src[j];
        float4 v = Y4[(size_t)s * 32 + l32];
        acc.x += v.x; acc.y += v.y; acc.z += v.z; acc.w += v.w;
    }

    // combine halves (lane l and l+32 hold the same columns)
    acc.x += __shfl_xor(acc.x, 32);
    acc.y += __shfl_xor(acc.y, 32);
    acc.z += __shfl_xor(acc.z, 32);
    acc.w += __shfl_xor(acc.w, 32);

    float di = dinv[node];
    float4 b = reinterpret_cast<const float4*>(bias)[l32];
    float4 h;
    h.x = fmaxf(acc.x * di + b.x, 0.f);
    h.y = fmaxf(acc.y * di + b.y, 0.f);
    h.z = fmaxf(acc.z * di + b.z, 0.f);
    h.w = fmaxf(acc.w * di + b.w, 0.f);

    if (!FUSE) {
        if (half == 0)
            reinterpret_cast<float4*>(out + (size_t)node * FDIM)[l32] = h;
    } else {
        if (half == 0) {
            // per-lane partial logits over this lane's 4 h components
            float lg[NCLS];
            #pragma unroll
            for (int c = 0; c < NCLS; ++c) {
                float4 w4 = *reinterpret_cast<const float4*>(&s_wl[c * FDIM + l32 * 4]);
                lg[c] = h.x * w4.x + h.y * w4.y + h.z * w4.z + h.w * w4.w;
            }
            // butterfly over the 32 lanes of half 0: all lanes get all 16 sums
            #pragma unroll
            for (int off = 1; off < 32; off <<= 1) {
                #pragma unroll
                for (int c = 0; c < NCLS; ++c) lg[c] += __shfl_xor(lg[c], off);
            }
            #pragma unroll
            for (int c = 0; c < NCLS; ++c) lg[c] += s_bl[c];
            // softmax (computed redundantly on all 32 lanes; static indexing only)
            float m = lg[0];
            #pragma unroll
            for (int c = 1; c < NCLS; ++c) m = fmaxf(m, lg[c]);
            float e[NCLS];
            float sum = 0.f;
            #pragma unroll
            for (int c = 0; c < NCLS; ++c) { e[c] = __expf(lg[c] - m); sum += e[c]; }
            float inv = 1.0f / sum;
            float mye = 0.f;
            #pragma unroll
            for (int c = 0; c < NCLS; ++c) if (l32 == c) mye = e[c];  // static idx, predicated
            if (l32 < NCLS) out[(size_t)node * NCLS + l32] = mye * inv;
        }
    }
}

extern "C" void kernel_launch(void* const* d_in, const int* in_sizes, int n_in,
                              void* d_out, int out_size, void* d_ws, size_t ws_size,
                              hipStream_t stream) {
    const float* x  = (const float*)d_in[0];
    const int*   ei = (const int*)d_in[1];
    const float* W1 = (const float*)d_in[2];
    const float* b1 = (const float*)d_in[3];
    const float* W2 = (const float*)d_in[4];
    const float* b2 = (const float*)d_in[5];
    const float* Wl = (const float*)d_in[6];
    const float* bl = (const float*)d_in[7];
    float* out = (float*)d_out;

    int n = in_sizes[0] / FDIM;
    int e = in_sizes[1] / 2;
    const int* src = ei;
    const int* dst = ei + e;

    int nb = (n + SCAN_CHUNK - 1) / SCAN_CHUNK;  // <=1024

    // workspace layout
    float* dinv    = (float*)d_ws;                     // n
    int*   cnt     = (int*)(dinv + n);                 // n
    int*   row_ptr = cnt + n;                          // n+1
    int*   cursor  = row_ptr + n + 1;                  // n
    int*   blockSum= cursor + n;                       // nb (<=1024)
    int*   total   = blockSum + 1024;                  // 1
    int*   csr_src = total + 1;                        // e
    float* bufA    = (float*)(csr_src + e);            // n*128
    float* bufB    = bufA + (size_t)n * FDIM;          // n*128

    int bn = (n + 255) / 256;
    int be = (e + 255) / 256;

    // CSR + norms
    k_zero_cnt<<<bn, 256, 0, stream>>>(cnt, n);
    k_count<<<be, 256, 0, stream>>>(dst, cnt, e);
    k_scan1<<<nb, SCAN_T, 0, stream>>>(cnt, row_ptr, blockSum, dinv, n);
    k_scan2<<<1, 1024, 0, stream>>>(blockSum, total, nb);
    k_scan3<<<bn, 256, 0, stream>>>(row_ptr, cursor, blockSum, total, n);
    k_scatter<<<be, 256, 0, stream>>>(src, dst, cursor, csr_src, e);

    int bg = (n + GR - 1) / GR;
    int ba = (n + 3) / 4;

    // layer 1
    k_gemm128<<<bg, GT, 0, stream>>>(x, W1, dinv, bufA, n);
    k_agg<false><<<ba, 256, 0, stream>>>(bufA, csr_src, row_ptr, dinv, b1, Wl, bl, bufB, n);

    // layer 2 (+ fused classifier/softmax)
    k_gemm128<<<bg, GT, 0, stream>>>(bufB, W2, dinv, bufA, n);
    k_agg<true><<<ba, 256, 0, stream>>>(bufA, csr_src, row_ptr, dinv, b2, Wl, bl, out, n);
}